// Round 4
// baseline (285.303 us; speedup 1.0000x reference)
//
#include <hip/hip_runtime.h>

#define NN 1024
#define CC 768
#define OO 768
#define RR 16
#define MM 8192
#define KK (CC*RR)      /* 12288 */
#define BM 128
#define BO 128
#define BK 64
#define KTILES (KK/BK)  /* 192 */
#define KHALF (KTILES/2)/* 96 */

typedef __bf16 bf16x8 __attribute__((ext_vector_type(8)));
typedef float  f32x4  __attribute__((ext_vector_type(4)));

// ---- prep ----
// B' layout (fragment order): element addr = (ot*192+kt)*8192 + o16*1024 + ks*512 + quad*128 + lrow*8 + j
//   where o = ot*128+o16*16+lrow, k = kt*64 + ks*32 + quad*8 + j  (k = c*16+r)
__global__ __launch_bounds__(256) void k_prep(const float* __restrict__ w,
                                              const float* __restrict__ coef,
                                              const float* __restrict__ bias,
                                              __bf16* __restrict__ bfrag,
                                              float* __restrict__ bterm,
                                              float* __restrict__ outz) {
    long id = blockIdx.x;
    if (id < 4608) {                       // 1,179,648 chunks of 8 elements; writes coalesced
        long t = id * 256 + threadIdx.x;
        int lrow = (int)(t & 15);
        int quad = (int)((t >> 4) & 3);
        int ks   = (int)((t >> 6) & 1);
        int o16  = (int)((t >> 7) & 7);
        int rest = (int)(t >> 10);         // 0..1151
        int kt = rest % 192, ot = rest / 192;
        int o = ot * 128 + o16 * 16 + lrow;
        int c = kt * 4 + ks * 2 + (quad >> 1);   // k = c*16 + (quad&1)*8 + j
        const float* src = w + ((long)o * CC + c) * RR + (quad & 1) * 8;
        float4 a = *(const float4*)src;
        float4 b = *(const float4*)(src + 4);
        bf16x8 v = {(__bf16)a.x, (__bf16)a.y, (__bf16)a.z, (__bf16)a.w,
                    (__bf16)b.x, (__bf16)b.y, (__bf16)b.z, (__bf16)b.w};
        *(bf16x8*)(bfrag + t * 8) = v;
    } else if (id < 7680) {                // bterm[n,o] = coef[n,:]·bias[o,:]
        int i = (int)(id - 4608) * 256 + threadIdx.x;
        int n = i / OO, o = i - n * OO;
        const float4* cp = (const float4*)(coef + n * RR);
        const float4* bp = (const float4*)(bias + o * RR);
        float s = 0.f;
#pragma unroll
        for (int q = 0; q < 4; ++q) {
            float4 c4 = cp[q], b4 = bp[q];
            s += c4.x * b4.x + c4.y * b4.y + c4.z * b4.z + c4.w * b4.w;
        }
        bterm[i] = s;
    } else {                               // zero d_out (6.29M floats)
        long u = ((id - 7680) * 256 + threadIdx.x) * 8;
        float4 z = {0.f, 0.f, 0.f, 0.f};
        *(float4*)(outz + u) = z;
        *(float4*)(outz + u + 4) = z;
    }
}

// ---- GEMM: A via dbuf-LDS build (1 barrier/kt), B-frags direct global->VGPR ----
__global__ __launch_bounds__(256, 3) void k_gemm(const float* __restrict__ x,
                                                 const float* __restrict__ coef,
                                                 const __bf16* __restrict__ bfrag,
                                                 const float* __restrict__ bterm,
                                                 float* __restrict__ out) {
    __shared__ __bf16 lA[2][BM * BK];      // 2 x 16 KB

    const int tid = threadIdx.x;

    // otile-major global order, id&7 = XCD -> each XCD's blocks share 1-2 otiles
    int g     = (blockIdx.x & 7) * 96 + (blockIdx.x >> 3);   // 0..767
    int ot    = g >> 7;                    // 0..5
    int rem   = g & 127;
    int kh    = rem & 1;
    int mtile = rem >> 1;                  // 0..63
    const int m0 = mtile * BM;
    const int kt0 = kh * KHALF, kt1 = kt0 + KHALF;

    // A-build mapping
    const int am     = tid & 127;
    const int ahalf  = tid >> 7;
    const int m_glob = m0 + am;
    const int n_idx  = m_glob & (NN - 1);
    const float* xrow = x + (long)m_glob * CC;

    float cf[16];
#pragma unroll
    for (int r = 0; r < 16; r += 4) {
        float4 t4 = *(const float4*)(coef + n_idx * RR + r);
        cf[r] = t4.x; cf[r + 1] = t4.y; cf[r + 2] = t4.z; cf[r + 3] = t4.w;
    }

    const int lane = tid & 63, wave = tid >> 6;
    const int wm = (wave & 1) * 64, wo = (wave >> 1) * 64;
    const int lrow = lane & 15, quad = lane >> 4;

    // per-lane B-frag base (advances 8192 elements per kt)
    const __bf16* Bk = bfrag + ((long)ot * 192 + kt0) * 8192
                     + (wo >> 4) * 1024 + quad * 128 + lrow * 8;

    f32x4 acc[4][4] = {};
    float2 x2 = *(const float2*)(xrow + kt0 * 4 + 2 * ahalf);

#pragma unroll 1
    for (int kt = kt0; kt < kt1; ++kt) {
        // --- B fragments: 8 coalesced 16B global loads (L1/L2-served) ---
        bf16x8 bfr[2][4];
#pragma unroll
        for (int ks = 0; ks < 2; ++ks)
#pragma unroll
            for (int io = 0; io < 4; ++io)
                bfr[ks][io] = *(const bf16x8*)(Bk + io * 1024 + ks * 512);
        Bk += 8192;

        // --- prefetch next x chunk ---
        float2 x2n = x2;
        if (kt + 1 < kt1) x2n = *(const float2*)(xrow + (kt + 1) * 4 + 2 * ahalf);

        // --- build A(kt) into lA[kt&1] (XOR-swizzled, conflict-free) ---
        __bf16* la = &lA[kt & 1][0];
#pragma unroll
        for (int ci = 0; ci < 2; ++ci) {
            float xv = ci ? x2.y : x2.x;
            int c_local = 2 * ahalf + ci;
#pragma unroll
            for (int rh = 0; rh < 2; ++rh) {
                bf16x8 v;
#pragma unroll
                for (int j = 0; j < 8; ++j) v[j] = (__bf16)(xv * cf[rh * 8 + j]);
                int kb = c_local * 2 + rh;
                *(bf16x8*)(&la[am * BK + ((kb ^ (am & 7)) * 8)]) = v;
            }
        }
        x2 = x2n;
        __syncthreads();   // single barrier: A(kt) writes visible; dbuf protects kt+1

        // --- compute: 2 k-steps x 16 MFMA ---
#pragma unroll
        for (int ks = 0; ks < 2; ++ks) {
            bf16x8 af[4];
            int kb = ks * 4 + quad;
#pragma unroll
            for (int im = 0; im < 4; ++im) {
                int row = wm + im * 16 + lrow;
                af[im] = *(const bf16x8*)(&la[row * BK + ((kb ^ (row & 7)) * 8)]);
            }
#pragma unroll
            for (int im = 0; im < 4; ++im)
#pragma unroll
                for (int io = 0; io < 4; ++io)
                    acc[im][io] = __builtin_amdgcn_mfma_f32_16x16x32_bf16(
                        af[im], bfr[ks][io], acc[im][io], 0, 0, 0);
        }
    }

    // ---- epilogue: atomic accumulate; kh==0 adds bterm ----
#pragma unroll
    for (int im = 0; im < 4; ++im) {
#pragma unroll
        for (int io = 0; io < 4; ++io) {
            int o = ot * BO + wo + io * 16 + lrow;
#pragma unroll
            for (int r = 0; r < 4; ++r) {
                int moff = wm + im * 16 + quad * 4 + r;
                long m = m0 + moff;
                int n = (int)(m & (NN - 1));
                float v = acc[im][io][r];
                if (kh == 0) v += bterm[(long)n * OO + o];
                atomicAdd(&out[m * OO + o], v);
            }
        }
    }
}

// ---- fallback if workspace too small (correctness-only) ----
__global__ void k_naive(const float* __restrict__ x, const float* __restrict__ coef,
                        const float* __restrict__ w, const float* __restrict__ bias,
                        float* __restrict__ out) {
    long i = (long)blockIdx.x * 256 + threadIdx.x;
    if (i >= (long)MM * OO) return;
    int o = (int)(i % OO);
    long m = i / OO;
    int n = (int)(m & (NN - 1));
    float cf[16];
#pragma unroll
    for (int r = 0; r < 16; ++r) cf[r] = coef[n * RR + r];
    const float* xr = x + m * CC;
    const float* wr = w + (long)o * CC * RR;
    float s = 0.f;
    for (int c = 0; c < CC; ++c) {
        float t = 0.f;
#pragma unroll
        for (int r = 0; r < 16; ++r) t += cf[r] * wr[c * RR + r];
        s += xr[c] * t;
    }
    float bs = 0.f;
#pragma unroll
    for (int r = 0; r < 16; ++r) bs += cf[r] * bias[o * RR + r];
    out[i] = s + bs;
}

extern "C" void kernel_launch(void* const* d_in, const int* in_sizes, int n_in,
                              void* d_out, int out_size, void* d_ws, size_t ws_size,
                              hipStream_t stream) {
    const float* x    = (const float*)d_in[0];
    const float* coef = (const float*)d_in[1];
    const float* w    = (const float*)d_in[2];
    const float* bias = (const float*)d_in[3];
    float* out = (float*)d_out;

    const size_t bfrag_bytes = (size_t)OO * KK * sizeof(__bf16);   // 18,874,368
    const size_t bt_bytes    = (size_t)NN * OO * sizeof(float);    //  3,145,728

    if (ws_size >= bfrag_bytes + bt_bytes) {
        __bf16* bfrag = (__bf16*)d_ws;
        float*  btrm  = (float*)((char*)d_ws + bfrag_bytes);
        k_prep<<<10752, 256, 0, stream>>>(w, coef, bias, bfrag, btrm, out);
        k_gemm<<<768, 256, 0, stream>>>(x, coef, bfrag, btrm, out);
    } else {
        k_naive<<<(int)(((long)MM * OO + 255) / 256), 256, 0, stream>>>(x, coef, w, bias, out);
    }
}